// Round 3
// baseline (936.267 us; speedup 1.0000x reference)
//
#include <hip/hip_runtime.h>
#include <cstdint>

#define DEV __device__ __forceinline__

constexpr int Bz = 8, Tz = 4096, Cz = 1024;
constexpr int Mz = Bz * Tz;           // 32768 rows
constexpr int Sz = 32, Lz = 128;      // scan: 32 chunks x 128 steps = T

using bf16x8  = __attribute__((ext_vector_type(8))) __bf16;
using floatx4 = __attribute__((ext_vector_type(4))) float;

DEV float bf2f(unsigned short u) { return __uint_as_float(((uint32_t)u) << 16); }
DEV unsigned short f2bf(float f) {            // round-to-nearest-even
    uint32_t u = __float_as_uint(f);
    u += 0x7fffu + ((u >> 16) & 1u);
    return (unsigned short)(u >> 16);
}
DEV unsigned short f2h(float f) {
    _Float16 h = (_Float16)f;
    unsigned short u;
    __builtin_memcpy(&u, &h, 2);
    return u;
}
DEV float h2f(unsigned short u) {
    _Float16 h;
    __builtin_memcpy(&h, &u, 2);
    return (float)h;
}

DEV void gl2lds16(const unsigned short* g, unsigned short* l) {
    __builtin_amdgcn_global_load_lds(
        (const __attribute__((address_space(1))) void*)g,
        (__attribute__((address_space(3))) void*)l, 16, 0, 0);
}

// s_waitcnt imm: vm[3:0], exp[6:4]=7(no wait), lgkm[11:8]=15(no wait), vm_hi[15:14]
#define WAITCNT_VM4() __builtin_amdgcn_s_waitcnt(0x0F74)
#define WAITCNT_VM0() __builtin_amdgcn_s_waitcnt(0x0F70)

// ---------------- weight fp32 -> bf16 (all 4 weights, one dispatch) ----------------
__global__ __launch_bounds__(256) void f2b_k(const float* __restrict__ w0,
                                             const float* __restrict__ w1,
                                             const float* __restrict__ w2,
                                             const float* __restrict__ w3,
                                             unsigned short* __restrict__ dst) {
    int which = blockIdx.y;
    const float* src = which == 0 ? w0 : which == 1 ? w1 : which == 2 ? w2 : w3;
    int i = blockIdx.x * 256 + threadIdx.x;          // float4 idx within one weight
    float4 v = ((const float4*)src)[i];
    ushort4 o;
    o.x = f2bf(v.x); o.y = f2bf(v.y); o.z = f2bf(v.z); o.w = f2bf(v.w);
    ((ushort4*)(dst + (size_t)which * Cz * Cz))[i] = o;
}

// ---------------- time-mix: xk/xv/xr (bf16) ----------------
DEV ushort4 mix4(float4 m, float4 xc, float4 xp) {
    ushort4 o;
    o.x = f2bf(fmaf(m.x, xc.x - xp.x, xp.x));
    o.y = f2bf(fmaf(m.y, xc.y - xp.y, xp.y));
    o.z = f2bf(fmaf(m.z, xc.z - xp.z, xp.z));
    o.w = f2bf(fmaf(m.w, xc.w - xp.w, xp.w));
    return o;
}

__global__ __launch_bounds__(256) void mix_k(const float* __restrict__ x,
    const float* __restrict__ mk, const float* __restrict__ mv, const float* __restrict__ mr,
    unsigned short* __restrict__ xk, unsigned short* __restrict__ xv,
    unsigned short* __restrict__ xr) {
    int gid = blockIdx.x * 256 + threadIdx.x;       // float4 group; total Mz*Cz/4
    int m   = gid >> 8;                             // row = b*T + t   (Cz/4 = 256)
    int c4  = gid & 255;
    float4 xc = ((const float4*)x)[gid];
    float4 xp = make_float4(0.f, 0.f, 0.f, 0.f);
    if ((m & (Tz - 1)) != 0) xp = ((const float4*)x)[gid - 256];   // x[b, t-1]
    ((ushort4*)xk)[gid] = mix4(((const float4*)mk)[c4], xc, xp);
    ((ushort4*)xv)[gid] = mix4(((const float4*)mv)[c4], xc, xp);
    ((ushort4*)xr)[gid] = mix4(((const float4*)mr)[c4], xc, xp);
}

// ---------------- bf16 NT GEMM, BK=32 double-buffered pipeline ----------------
// C[m,n] = sum_k A[m,k] * Bw[n,k];  M=32768, N=K=1024
// LDS in MFMA-fragment order: chunk q = mi*64 + lane holds
//   A[m0 + mi*16 + (q&15)][kt*32 + ((q>>4)&3)*8 .. +8]  -> frag reads are 64
//   consecutive 16B chunks per wave = conflict-free ds_read_b128.
// grid (8, 256, nz); z selects A/out/mode.  modes packed 4b each:
//   0: fp32 store; 1: bf16; 2: sigmoid->bf16; 3: f16
__global__ __launch_bounds__(256) void gemm_bt(
        const unsigned short* __restrict__ A0, const unsigned short* __restrict__ A1,
        const unsigned short* __restrict__ A2,
        const unsigned short* __restrict__ Bw0, const unsigned short* __restrict__ Bw1,
        const unsigned short* __restrict__ Bw2,
        void* __restrict__ O0, void* __restrict__ O1, void* __restrict__ O2,
        int modes) {
    constexpr int Kd = 1024, Nd = 1024;
    __shared__ unsigned short lA[2][128 * 32];   // 2 x 8 KB
    __shared__ unsigned short lB[2][128 * 32];   // 2 x 8 KB

    const int z = blockIdx.z;
    const unsigned short* A  = z == 0 ? A0  : z == 1 ? A1  : A2;
    const unsigned short* Bw = z == 0 ? Bw0 : z == 1 ? Bw1 : Bw2;
    void* Cout = z == 0 ? O0 : z == 1 ? O1 : O2;
    const int mode = (modes >> (z * 4)) & 15;

    // XCD swizzle: round-robin over 8 XCDs; the 8 n-blocks sharing one A
    // row-slice land adjacent on ONE xcd (kept from R2: FETCH 140->62 MB).
    const int L    = blockIdx.y * 8 + blockIdx.x;   // dispatch-linear id, 0..2047
    const int xcd  = L & 7, slot = L >> 3;
    const int mb   = xcd * 32 + (slot >> 3);        // 0..255
    const int nb   = slot & 7;                      // 0..7
    const int m0   = mb * 128, n0 = nb * 128;

    const int tid  = threadIdx.x;
    const int lane = tid & 63;
    const int wave = tid >> 6;
    const int wm   = (wave >> 1) * 64, wn = (wave & 1) * 64;
    const int l15  = lane & 15, kseg = lane >> 4;

    // staging addresses (fragment-order gather): thread t covers chunk q0=t and
    // q1=t+256: row = ((q>>6)<<4) + (q&15), kcol-chunk = ((q>>4)&3)*8.
    // q1 is q0 shifted by 64 rows, same kcol. Same global address set as a
    // row-major gather -> identical coalescing.
    const int arow = ((tid >> 6) << 4) + (tid & 15);
    const int akc  = ((tid >> 4) & 3) * 8;
    const unsigned short* gA = A  + (size_t)(m0 + arow) * Kd + akc;
    const unsigned short* gB = Bw + (size_t)(n0 + arow) * Kd + akc;

    floatx4 acc[4][4];
#pragma unroll
    for (int mi = 0; mi < 4; mi++)
#pragma unroll
        for (int ni = 0; ni < 4; ni++) acc[mi][ni] = (floatx4){0.f, 0.f, 0.f, 0.f};

#define ISSUE(buf, kt) do {                                            \
        gl2lds16(gA + (kt) * 32,                   &lA[buf][tid * 8]); \
        gl2lds16(gA + (kt) * 32 + (size_t)64 * Kd, &lA[buf][2048 + tid * 8]); \
        gl2lds16(gB + (kt) * 32,                   &lB[buf][tid * 8]); \
        gl2lds16(gB + (kt) * 32 + (size_t)64 * Kd, &lB[buf][2048 + tid * 8]); \
    } while (0)

    ISSUE(0, 0);

    const int fa = wm >> 4, fb = wn >> 4;   // frag-group bases (0 or 4)
#pragma unroll 2
    for (int kt = 0; kt < 32; ++kt) {
        const int cur = kt & 1;
        if (kt < 31) {
            ISSUE(cur ^ 1, kt + 1);
            WAITCNT_VM4();      // stage-kt loads landed; next stage stays in flight
        } else {
            WAITCNT_VM0();
        }
        __builtin_amdgcn_s_barrier();
        asm volatile("" ::: "memory");

        const unsigned short* pA = lA[cur];
        const unsigned short* pB = lB[cur];
        bf16x8 af[4], bfr[4];
#pragma unroll
        for (int i = 0; i < 4; i++) {
            af[i]  = *(const bf16x8*)(pA + (fa + i) * 512 + lane * 8);
            bfr[i] = *(const bf16x8*)(pB + (fb + i) * 512 + lane * 8);
        }
#pragma unroll
        for (int mi = 0; mi < 4; mi++)
#pragma unroll
            for (int ni = 0; ni < 4; ni++)
                acc[mi][ni] = __builtin_amdgcn_mfma_f32_16x16x32_bf16(
                    af[mi], bfr[ni], acc[mi][ni], 0, 0, 0);

        asm volatile("" ::: "memory");
        __builtin_amdgcn_s_barrier();   // readers done before buf[cur] is re-issued
    }
#undef ISSUE

    // epilogue: D col = lane&15, row = (lane>>4)*4 + reg   [m89 verified]
    const int cr = kseg * 4;
#pragma unroll
    for (int mi = 0; mi < 4; mi++) {
#pragma unroll
        for (int ni = 0; ni < 4; ni++) {
            size_t row = (size_t)(m0 + wm + mi * 16 + cr);
            size_t col = (size_t)(n0 + wn + ni * 16 + l15);
#pragma unroll
            for (int rg = 0; rg < 4; rg++) {
                float v = acc[mi][ni][rg];
                size_t idx = (row + rg) * Nd + col;
                if (mode == 0) {
                    ((float*)Cout)[idx] = v;
                } else if (mode == 1) {
                    ((unsigned short*)Cout)[idx] = f2bf(v);
                } else if (mode == 2) {
                    float sg = 1.0f / (1.0f + __expf(-v));
                    ((unsigned short*)Cout)[idx] = f2bf(sg);
                } else {
                    ((unsigned short*)Cout)[idx] = f2h(v);
                }
            }
        }
    }
}

// ---------------- WKV scan, 3-pass chunked linear recurrence ----------------
// unnormalized state: A_t = lam*A + e^k * v ; B_t = lam*B + e^k  (fp32-safe:
// |k|<~6, 1/(1-lam)<=400 -> state in [e^-6, ~1e5])
// 2 channels per thread; k stored f16, v/r bf16.

__global__ __launch_bounds__(256) void wkv_pass1(const unsigned short* __restrict__ kh,
    const unsigned short* __restrict__ vb, const float* __restrict__ td,
    float2* __restrict__ SA, float2* __restrict__ SB) {
    int tid = blockIdx.x * 256 + threadIdx.x;   // B*S*C/2 threads
    int c2  = tid & 511;
    int bs  = tid >> 9;                         // b*S + s
    int b   = bs >> 5, s = bs & (Sz - 1);
    int c   = c2 * 2;
    float lam0 = __expf(-__expf(td[c]));
    float lam1 = __expf(-__expf(td[c + 1]));
    size_t base = (((size_t)(b * Tz + s * Lz)) * Cz + c) >> 1;   // ushort2 index
    float pa0 = 0.f, pb0 = 0.f, pa1 = 0.f, pb1 = 0.f;
#pragma unroll 4
    for (int i = 0; i < Lz; i++) {
        size_t idx = base + (size_t)i * (Cz / 2);
        ushort2 kk = ((const ushort2*)kh)[idx];
        ushort2 vv = ((const ushort2*)vb)[idx];
        float e0 = __expf(h2f(kk.x)), e1 = __expf(h2f(kk.y));
        pa0 = fmaf(pa0, lam0, e0 * bf2f(vv.x));
        pb0 = fmaf(pb0, lam0, e0);
        pa1 = fmaf(pa1, lam1, e1 * bf2f(vv.y));
        pb1 = fmaf(pb1, lam1, e1);
    }
    SA[tid] = make_float2(pa0, pa1);   // layout (b*S+s)*512 + c2
    SB[tid] = make_float2(pb0, pb1);
}

__global__ __launch_bounds__(256) void wkv_pass2(const float* __restrict__ td,
                                                 float2* __restrict__ SA,
                                                 float2* __restrict__ SB) {
    int tid = blockIdx.x * 256 + threadIdx.x;   // B*C/2 threads
    int c2  = tid & 511;
    int b   = tid >> 9;
    int c   = c2 * 2;
    float lamL0 = __expf(-__expf(td[c]) * (float)Lz);
    float lamL1 = __expf(-__expf(td[c + 1]) * (float)Lz);
    float A0 = 0.f, B0 = 0.f, A1 = 0.f, B1 = 0.f;
    for (int s = 0; s < Sz; s++) {
        size_t idx = ((size_t)(b * Sz + s)) * 512 + c2;
        float2 ta = SA[idx], tb = SB[idx];
        SA[idx] = make_float2(A0, A1);          // exclusive prefix = chunk-start state
        SB[idx] = make_float2(B0, B1);
        A0 = fmaf(A0, lamL0, ta.x);  B0 = fmaf(B0, lamL0, tb.x);
        A1 = fmaf(A1, lamL1, ta.y);  B1 = fmaf(B1, lamL1, tb.y);
    }
}

__global__ __launch_bounds__(256) void wkv_pass3(const unsigned short* __restrict__ kh,
    const unsigned short* __restrict__ vb, const unsigned short* __restrict__ rb,
    const float* __restrict__ td, const float* __restrict__ tf,
    const float2* __restrict__ SA, const float2* __restrict__ SB,
    unsigned short* __restrict__ ry) {
    int tid = blockIdx.x * 256 + threadIdx.x;
    int c2  = tid & 511;
    int bs  = tid >> 9;
    int b   = bs >> 5, s = bs & (Sz - 1);
    int c   = c2 * 2;
    float lam0 = __expf(-__expf(td[c]));
    float lam1 = __expf(-__expf(td[c + 1]));
    float eu0  = __expf(tf[c]);
    float eu1  = __expf(tf[c + 1]);
    float2 fa = SA[tid], fb = SB[tid];
    float A0 = fa.x, A1 = fa.y, B0 = fb.x, B1 = fb.y;
    size_t base = (((size_t)(b * Tz + s * Lz)) * Cz + c) >> 1;
#pragma unroll 2
    for (int i = 0; i < Lz; i++) {
        size_t idx = base + (size_t)i * (Cz / 2);
        ushort2 kk = ((const ushort2*)kh)[idx];
        ushort2 vv = ((const ushort2*)vb)[idx];
        ushort2 rr = ((const ushort2*)rb)[idx];
        float e0 = __expf(h2f(kk.x)), e1 = __expf(h2f(kk.y));
        float ev0 = e0 * bf2f(vv.x), ev1 = e1 * bf2f(vv.y);
        float y0 = fmaf(A0, eu0, ev0) * __builtin_amdgcn_rcpf(fmaf(B0, eu0, e0));
        float y1 = fmaf(A1, eu1, ev1) * __builtin_amdgcn_rcpf(fmaf(B1, eu1, e1));
        ushort2 o;
        o.x = f2bf(bf2f(rr.x) * y0);
        o.y = f2bf(bf2f(rr.y) * y1);
        ((ushort2*)ry)[idx] = o;
        A0 = fmaf(A0, lam0, ev0);  B0 = fmaf(B0, lam0, e0);
        A1 = fmaf(A1, lam1, ev1);  B1 = fmaf(B1, lam1, e1);
    }
}

// ---------------- launcher ----------------
extern "C" void kernel_launch(void* const* d_in, const int* in_sizes, int n_in,
                              void* d_out, int out_size, void* d_ws, size_t ws_size,
                              hipStream_t stream) {
    const float* x  = (const float*)d_in[0];
    const float* td = (const float*)d_in[1];
    const float* tf = (const float*)d_in[2];
    const float* mk = (const float*)d_in[3];
    const float* mv = (const float*)d_in[4];
    const float* mr = (const float*)d_in[5];
    const float* Wk = (const float*)d_in[6];
    const float* Wv = (const float*)d_in[7];
    const float* Wr = (const float*)d_in[8];
    const float* Wo = (const float*)d_in[9];

    constexpr size_t SZ_BF = (size_t)Mz * Cz * 2;       // 64 MB
    constexpr size_t SZ_W  = (size_t)Cz * Cz * 2;       // 2 MB
    constexpr size_t SZ_S  = (size_t)Bz * Sz * Cz * 4;  // 1 MB

    char* ws = (char*)d_ws;
    unsigned short* xk  = (unsigned short*)(ws);
    unsigned short* xv  = (unsigned short*)(ws + SZ_BF);
    unsigned short* xr  = (unsigned short*)(ws + 2 * SZ_BF);
    unsigned short* kf  = (unsigned short*)(ws + 3 * SZ_BF);   // f16
    unsigned short* vb  = (unsigned short*)(ws + 4 * SZ_BF);   // bf16
    unsigned short* rb  = (unsigned short*)(ws + 5 * SZ_BF);   // bf16
    unsigned short* wts = (unsigned short*)(ws + 6 * SZ_BF);   // wk|wv|wr|wo
    float2*         SA  = (float2*)        (ws + 6 * SZ_BF + 4 * SZ_W);
    float2*         SB  = (float2*)        (ws + 6 * SZ_BF + 4 * SZ_W + SZ_S);
    unsigned short* wkb = wts;
    unsigned short* wvb = wts + (size_t)Cz * Cz;
    unsigned short* wrb = wts + (size_t)2 * Cz * Cz;
    unsigned short* wob = wts + (size_t)3 * Cz * Cz;
    unsigned short* ry  = xk;   // xk dead after k-GEMM; reuse for r*y

    f2b_k<<<dim3(Cz * Cz / 4 / 256, 4), dim3(256), 0, stream>>>(Wk, Wv, Wr, Wo, wts);

    mix_k<<<dim3(Mz * Cz / 4 / 256), dim3(256), 0, stream>>>(x, mk, mv, mr, xk, xv, xr);

    // fused k/v/r GEMMs: z=0 k->f16, z=1 v->bf16, z=2 r->sigmoid bf16
    gemm_bt<<<dim3(8, 256, 3), dim3(256), 0, stream>>>(
        xk, xv, xr, wkb, wvb, wrb, (void*)kf, (void*)vb, (void*)rb,
        (3) | (1 << 4) | (2 << 8));

    wkv_pass1<<<dim3(Bz * Sz * Cz / 2 / 256), dim3(256), 0, stream>>>(kf, vb, td, SA, SB);
    wkv_pass2<<<dim3(Bz * Cz / 2 / 256), dim3(256), 0, stream>>>(td, SA, SB);
    wkv_pass3<<<dim3(Bz * Sz * Cz / 2 / 256), dim3(256), 0, stream>>>(kf, vb, rb, td, tf,
                                                                      SA, SB, ry);

    // out = (r*y) @ Wo^T, fp32
    gemm_bt<<<dim3(8, 256, 1), dim3(256), 0, stream>>>(
        ry, ry, ry, wob, wob, wob, d_out, d_out, d_out, 0);
}